// Round 2
// baseline (309.948 us; speedup 1.0000x reference)
//
#include <hip/hip_runtime.h>

#define DIM 1024
#define HEADS 16
#define HD 64
#define BATCH 2
#define SEQ 2048
#define ROWS (BATCH*SEQ)          // 4096
#define EPS 1e-6f

typedef float f32x4  __attribute__((ext_vector_type(4)));
typedef float f32x16 __attribute__((ext_vector_type(16)));
typedef short s16x8  __attribute__((ext_vector_type(8)));

static __device__ __forceinline__ short f2bf(float f) {
    union { float f; unsigned u; } x; x.f = f;
    unsigned r = x.u + 0x7FFFu + ((x.u >> 16) & 1u);
    return (short)(r >> 16);
}
static __device__ __forceinline__ float bf2f(short s) {
    union { unsigned u; float f; } x; x.u = ((unsigned)(unsigned short)s) << 16;
    return x.f;
}
static __device__ __forceinline__ s16x8 pack8(float4 lo, float4 hi) {
    s16x8 r;
    r[0]=f2bf(lo.x); r[1]=f2bf(lo.y); r[2]=f2bf(lo.z); r[3]=f2bf(lo.w);
    r[4]=f2bf(hi.x); r[5]=f2bf(hi.y); r[6]=f2bf(hi.z); r[7]=f2bf(hi.w);
    return r;
}
static __device__ __forceinline__ unsigned cvtpk(float a, float b) {
    unsigned r;
    asm("v_cvt_pk_bf16_f32 %0, %1, %2" : "=v"(r) : "v"(a), "v"(b));
    return r;
}

#define MFMA32(A,B,C) __builtin_amdgcn_mfma_f32_32x32x16_bf16(A, B, C, 0, 0, 0)

// ---------------------------------------------------------------------------
// GEMM: C[M][Ncols] = A[M][K] * W[Ncols][K]^T   (A,W fp32; compute bf16 MFMA)
// MODE 0: epilogue scatters bf16 q/k to [B,H,N,D] and v to V^T [B,H,D,N]
// MODE 1: epilogue adds bias and writes fp32 to out (proj gemm)
// ---------------------------------------------------------------------------
#define BM 128
#define BN 128
#define BK 32
#define LDT 40   // LDS row stride in shorts

template<int MODE>
__global__ __launch_bounds__(256) void gemm_kernel(
    const float* __restrict__ A, const float* __restrict__ W,
    const float* __restrict__ bias,
    short* __restrict__ qb, short* __restrict__ kb, short* __restrict__ vb,
    float* __restrict__ out)
{
    alignas(16) __shared__ short As[BM*LDT];
    alignas(16) __shared__ short Bs[BN*LDT];
    const int tid  = threadIdx.x;
    const int lane = tid & 63, wave = tid >> 6;
    const int wr = wave >> 1, wc = wave & 1;
    const int c = lane & 15, g = lane >> 4;
    const int brow = blockIdx.y * BM, bcol = blockIdx.x * BN;
    const int sr = tid >> 1, sk = (tid & 1) * 16;

    f32x4 acc[4][4] = {};

    for (int k0 = 0; k0 < DIM; k0 += BK) {
        const float4* pa = (const float4*)(A + (size_t)(brow + sr) * DIM + k0 + sk);
        const float4* pb = (const float4*)(W + (size_t)(bcol + sr) * DIM + k0 + sk);
        float4 a0 = pa[0], a1 = pa[1], a2 = pa[2], a3 = pa[3];
        float4 b0 = pb[0], b1 = pb[1], b2 = pb[2], b3 = pb[3];
        *(s16x8*)&As[sr*LDT + sk]     = pack8(a0, a1);
        *(s16x8*)&As[sr*LDT + sk + 8] = pack8(a2, a3);
        *(s16x8*)&Bs[sr*LDT + sk]     = pack8(b0, b1);
        *(s16x8*)&Bs[sr*LDT + sk + 8] = pack8(b2, b3);
        __syncthreads();

        s16x8 af[4], bf[4];
        #pragma unroll
        for (int m = 0; m < 4; m++)
            af[m] = *(const s16x8*)&As[(wr*64 + m*16 + c)*LDT + g*8];
        #pragma unroll
        for (int n = 0; n < 4; n++)
            bf[n] = *(const s16x8*)&Bs[(wc*64 + n*16 + c)*LDT + g*8];
        #pragma unroll
        for (int m = 0; m < 4; m++)
            #pragma unroll
            for (int n = 0; n < 4; n++)
                acc[m][n] = __builtin_amdgcn_mfma_f32_16x16x32_bf16(af[m], bf[n], acc[m][n], 0, 0, 0);
        __syncthreads();
    }

    if (MODE == 0) {
        #pragma unroll
        for (int n = 0; n < 4; n++) {
            int col = bcol + wc*64 + n*16 + c;
            int t = col >> 10, h = (col >> 6) & 15, d = col & 63;
            #pragma unroll
            for (int m = 0; m < 4; m++) {
                #pragma unroll
                for (int j = 0; j < 4; j++) {
                    int row = brow + wr*64 + m*16 + g*4 + j;
                    int bi = row >> 11, ni = row & (SEQ-1);
                    short val = f2bf(acc[m][n][j]);
                    if (t == 2)       vb[((size_t)(bi*HEADS + h)*HD + d)*SEQ + ni] = val;
                    else if (t == 1)  kb[(((size_t)(bi*HEADS + h))*SEQ + ni)*HD + d] = val;
                    else              qb[(((size_t)(bi*HEADS + h))*SEQ + ni)*HD + d] = val;
                }
            }
        }
    } else {
        #pragma unroll
        for (int n = 0; n < 4; n++) {
            int col = bcol + wc*64 + n*16 + c;
            float bv = bias[col];
            #pragma unroll
            for (int m = 0; m < 4; m++) {
                #pragma unroll
                for (int j = 0; j < 4; j++) {
                    int row = brow + wr*64 + m*16 + g*4 + j;
                    out[(size_t)row*DIM + col] = acc[m][n][j] + bv;
                }
            }
        }
    }
}

// ---------------------------------------------------------------------------
// LayerNorm over head_dim=64 for q and k. q gets D^-0.5 * log2(e) folded in
// (attention uses exp2 directly).
// ---------------------------------------------------------------------------
__global__ __launch_bounds__(256) void ln_qk(
    short* __restrict__ qb, short* __restrict__ kb,
    const float* __restrict__ qg, const float* __restrict__ qbeta,
    const float* __restrict__ kg, const float* __restrict__ kbeta)
{
    const int gw = blockIdx.x * 4 + (threadIdx.x >> 6);
    const int lane = threadIdx.x & 63;
    const int per = BATCH*HEADS*SEQ;
    const int which = gw >= per;
    const int row = which ? gw - per : gw;
    short* buf = which ? kb : qb;
    const float* gamma = which ? kg : qg;
    const float* beta  = which ? kbeta : qbeta;
    const float scale  = which ? 1.0f : (0.125f * 1.44269504088896340736f);

    short* p = buf + (size_t)row * HD;
    float v = bf2f(p[lane]);
    float s = v;
    #pragma unroll
    for (int m = 32; m; m >>= 1) s += __shfl_xor(s, m);
    float mu = s * (1.0f/64.0f);
    float d = v - mu;
    float vs = d * d;
    #pragma unroll
    for (int m = 32; m; m >>= 1) vs += __shfl_xor(vs, m);
    float rstd = rsqrtf(vs * (1.0f/64.0f) + EPS);
    p[lane] = f2bf((d * rstd * gamma[lane] + beta[lane]) * scale);
}

// ---------------------------------------------------------------------------
// Flash attention, swapped-operand 32x32 MFMA, no LDS, no barriers.
// Each wave owns 32 q rows. S^T = mfma(K,Q): lane holds P-row for q=lane&31.
// O^T = mfma(V^T, P): lane's O columns are its own q -> rescale lane-local.
// q pre-scaled by D^-0.5*log2e; exp2 used throughout.
// ---------------------------------------------------------------------------
__global__ __launch_bounds__(256) void attn_kernel(
    const short* __restrict__ qbuf, const short* __restrict__ kbuf,
    const short* __restrict__ vtbuf, float* __restrict__ aout)
{
    const int bh = blockIdx.x;
    const int wave = threadIdx.x >> 6, lane = threadIdx.x & 63;
    const int l31 = lane & 31, hi = lane >> 5;
    const int qb_i = blockIdx.y * 4 + wave;        // 64 q-blocks per bh
    const int q0 = qb_i * 32;
    const size_t base = (size_t)bh * SEQ * HD;
    const short* Q  = qbuf  + base;
    const short* K  = kbuf  + base;
    const short* VT = vtbuf + base;                // [HD][SEQ]

    // Q fragments: qf[ks][e] = Q[q0+l31][16ks+8hi+e]
    s16x8 qf[4];
    const short* qrow = Q + (size_t)(q0 + l31)*HD + 8*hi;
    #pragma unroll
    for (int ks = 0; ks < 4; ks++) qf[ks] = *(const s16x8*)(qrow + 16*ks);

    f32x16 o0 = {}, o1 = {};
    float m = -1e30f, l = 0.f;

    for (int kt = 0; kt < SEQ; kt += 64) {
        // S^T: two 32x32 fragments (keys kt..kt+31, kt+32..kt+63)
        f32x16 s0 = {}, s1 = {};
        const short* kbase = K + (size_t)(kt + l31)*HD + 8*hi;
        #pragma unroll
        for (int ks = 0; ks < 4; ks++) {
            s16x8 kf0 = *(const s16x8*)(kbase + 16*ks);
            s16x8 kf1 = *(const s16x8*)(kbase + 32*HD + 16*ks);
            s0 = MFMA32(kf0, qf[ks], s0);
            s1 = MFMA32(kf1, qf[ks], s1);
        }

        // lane-local softmax for q = q0+l31 (keys split across hi halves)
        float pmax;
        {
            float t[16];
            #pragma unroll
            for (int i = 0; i < 16; i++) t[i] = fmaxf(s0[i], s1[i]);
            #pragma unroll
            for (int st = 8; st > 0; st >>= 1)
                #pragma unroll
                for (int i = 0; i < st; i++) t[i] = fmaxf(t[i], t[i+st]);
            pmax = t[0];
        }
        pmax = fmaxf(pmax, __shfl_xor(pmax, 32));
        float mn = fmaxf(m, pmax);
        float corr = exp2f(m - mn);
        #pragma unroll
        for (int i = 0; i < 16; i++) {
            s0[i] = exp2f(s0[i] - mn);
            s1[i] = exp2f(s1[i] - mn);
        }
        float rs;
        {
            float t[16];
            #pragma unroll
            for (int i = 0; i < 16; i++) t[i] = s0[i] + s1[i];
            #pragma unroll
            for (int st = 8; st > 0; st >>= 1)
                #pragma unroll
                for (int i = 0; i < st; i++) t[i] += t[i+st];
            rs = t[0];
        }
        rs += __shfl_xor(rs, 32);
        l = l*corr + rs;
        m = mn;
        #pragma unroll
        for (int i = 0; i < 16; i++) { o0[i] *= corr; o1[i] *= corr; }

        // P -> bf16 A-fragments via cvt_pk + permlane32_swap (T12)
        // pa[ks][e] = P[q=l31][16ks + 8hi + e]
        s16x8 pa[4];
        #pragma unroll
        for (int ks = 0; ks < 4; ks++) {
            const int rb = 8*(ks & 1);
            unsigned A0, A1, B0, B1;
            if (ks < 2) {
                A0 = cvtpk(s0[rb+0], s0[rb+1]); A1 = cvtpk(s0[rb+2], s0[rb+3]);
                B0 = cvtpk(s0[rb+4], s0[rb+5]); B1 = cvtpk(s0[rb+6], s0[rb+7]);
            } else {
                A0 = cvtpk(s1[rb+0], s1[rb+1]); A1 = cvtpk(s1[rb+2], s1[rb+3]);
                B0 = cvtpk(s1[rb+4], s1[rb+5]); B1 = cvtpk(s1[rb+6], s1[rb+7]);
            }
            asm volatile("v_permlane32_swap_b32 %0, %1" : "+v"(A0), "+v"(B0));
            asm volatile("v_permlane32_swap_b32 %0, %1" : "+v"(A1), "+v"(B1));
            union { s16x8 v; unsigned u[4]; } w;
            w.u[0] = A0; w.u[1] = A1; w.u[2] = B0; w.u[3] = B1;
            pa[ks] = w.v;
        }

        // O^T += V^T * P   (vf rows = channel, pa cols = q)
        const short* vbase = VT + (size_t)l31*SEQ + kt + 8*hi;
        #pragma unroll
        for (int ks = 0; ks < 4; ks++) {
            s16x8 vf0 = *(const s16x8*)(vbase + 16*ks);
            s16x8 vf1 = *(const s16x8*)(vbase + 32*SEQ + 16*ks);
            o0 = MFMA32(vf0, pa[ks], o0);
            o1 = MFMA32(vf1, pa[ks], o1);
        }
    }

    // epilogue: lane writes its own q row; ch = 32c + (reg&3)+8*(reg>>2)+4hi
    const int b = bh >> 4, h = bh & 15;
    const float invl = 1.0f / l;
    float* dst = aout + ((size_t)(b*SEQ + q0 + l31))*DIM + h*HD;
    #pragma unroll
    for (int t = 0; t < 4; t++) {
        f32x4 w0, w1;
        #pragma unroll
        for (int j = 0; j < 4; j++) { w0[j] = o0[4*t + j]*invl; w1[j] = o1[4*t + j]*invl; }
        *(f32x4*)(dst + 8*t + 4*hi)      = w0;
        *(f32x4*)(dst + 32 + 8*t + 4*hi) = w1;
    }
}

// ---------------------------------------------------------------------------
extern "C" void kernel_launch(void* const* d_in, const int* in_sizes, int n_in,
                              void* d_out, int out_size, void* d_ws, size_t ws_size,
                              hipStream_t stream)
{
    const float* x     = (const float*)d_in[0];
    const float* Wqkv  = (const float*)d_in[1];
    const float* qg    = (const float*)d_in[2];
    const float* qbeta = (const float*)d_in[3];
    const float* kg    = (const float*)d_in[4];
    const float* kbeta = (const float*)d_in[5];
    const float* Wproj = (const float*)d_in[6];
    const float* bproj = (const float*)d_in[7];
    float* out = (float*)d_out;

    char* ws = (char*)d_ws;
    const size_t qkv_elems = (size_t)BATCH*HEADS*SEQ*HD;   // 4,194,304
    short* q  = (short*)(ws);
    short* k  = (short*)(ws + qkv_elems*2);
    short* vt = (short*)(ws + qkv_elems*4);                // V^T [B,H,D,N]
    float* aout = (float*)(ws + qkv_elems*6);              // [ROWS][DIM] fp32

    gemm_kernel<0><<<dim3(3*DIM/BN, ROWS/BM), 256, 0, stream>>>(
        x, Wqkv, nullptr, q, k, vt, nullptr);

    ln_qk<<<dim3(2*BATCH*HEADS*SEQ/4), 256, 0, stream>>>(q, k, qg, qbeta, kg, kbeta);

    attn_kernel<<<dim3(BATCH*HEADS, SEQ/32/4), 256, 0, stream>>>(q, k, vt, aout);

    gemm_kernel<1><<<dim3(DIM/BN, ROWS/BM), 256, 0, stream>>>(
        aout, Wproj, bproj, nullptr, nullptr, nullptr, out);
}

// Round 3
// 255.368 us; speedup vs baseline: 1.2137x; 1.2137x over previous
//
#include <hip/hip_runtime.h>

#define DIM 1024
#define HEADS 16
#define HD 64
#define BATCH 2
#define SEQ 2048
#define ROWS (BATCH*SEQ)          // 4096
#define EPS 1e-6f

typedef float f32x4  __attribute__((ext_vector_type(4)));
typedef float f32x16 __attribute__((ext_vector_type(16)));
typedef short s16x8  __attribute__((ext_vector_type(8)));

static __device__ __forceinline__ short f2bf(float f) {
    union { float f; unsigned u; } x; x.f = f;
    unsigned r = x.u + 0x7FFFu + ((x.u >> 16) & 1u);
    return (short)(r >> 16);
}
static __device__ __forceinline__ float bf2f(short s) {
    union { unsigned u; float f; } x; x.u = ((unsigned)(unsigned short)s) << 16;
    return x.f;
}
static __device__ __forceinline__ s16x8 pack8(float4 lo, float4 hi) {
    s16x8 r;
    r[0]=f2bf(lo.x); r[1]=f2bf(lo.y); r[2]=f2bf(lo.z); r[3]=f2bf(lo.w);
    r[4]=f2bf(hi.x); r[5]=f2bf(hi.y); r[6]=f2bf(hi.z); r[7]=f2bf(hi.w);
    return r;
}
static __device__ __forceinline__ unsigned cvtpk(float a, float b) {
    unsigned r;
    asm("v_cvt_pk_bf16_f32 %0, %1, %2" : "=v"(r) : "v"(a), "v"(b));
    return r;
}

#define MFMA32(A,B,C) __builtin_amdgcn_mfma_f32_32x32x16_bf16(A, B, C, 0, 0, 0)

// ---------------------------------------------------------------------------
// GEMM: C[M][Ncols] = A[M][K] * W[Ncols][K]^T   (A,W fp32; compute bf16 MFMA)
// MODE 0: epilogue scatters bf16 q/k/v to [B,H,N,D] (all row-major, coalesced)
// MODE 1: epilogue adds bias and writes fp32 to out (proj gemm)
// ---------------------------------------------------------------------------
#define BM 128
#define BN 128
#define BK 32
#define LDT 40   // LDS row stride in shorts

template<int MODE>
__global__ __launch_bounds__(256) void gemm_kernel(
    const float* __restrict__ A, const float* __restrict__ W,
    const float* __restrict__ bias,
    short* __restrict__ qb, short* __restrict__ kb, short* __restrict__ vb,
    float* __restrict__ out)
{
    alignas(16) __shared__ short As[BM*LDT];
    alignas(16) __shared__ short Bs[BN*LDT];
    const int tid  = threadIdx.x;
    const int lane = tid & 63, wave = tid >> 6;
    const int wr = wave >> 1, wc = wave & 1;
    const int c = lane & 15, g = lane >> 4;
    const int brow = blockIdx.y * BM, bcol = blockIdx.x * BN;
    const int sr = tid >> 1, sk = (tid & 1) * 16;

    f32x4 acc[4][4] = {};

    for (int k0 = 0; k0 < DIM; k0 += BK) {
        const float4* pa = (const float4*)(A + (size_t)(brow + sr) * DIM + k0 + sk);
        const float4* pb = (const float4*)(W + (size_t)(bcol + sr) * DIM + k0 + sk);
        float4 a0 = pa[0], a1 = pa[1], a2 = pa[2], a3 = pa[3];
        float4 b0 = pb[0], b1 = pb[1], b2 = pb[2], b3 = pb[3];
        *(s16x8*)&As[sr*LDT + sk]     = pack8(a0, a1);
        *(s16x8*)&As[sr*LDT + sk + 8] = pack8(a2, a3);
        *(s16x8*)&Bs[sr*LDT + sk]     = pack8(b0, b1);
        *(s16x8*)&Bs[sr*LDT + sk + 8] = pack8(b2, b3);
        __syncthreads();

        s16x8 af[4], bf[4];
        #pragma unroll
        for (int m = 0; m < 4; m++)
            af[m] = *(const s16x8*)&As[(wr*64 + m*16 + c)*LDT + g*8];
        #pragma unroll
        for (int n = 0; n < 4; n++)
            bf[n] = *(const s16x8*)&Bs[(wc*64 + n*16 + c)*LDT + g*8];
        #pragma unroll
        for (int m = 0; m < 4; m++)
            #pragma unroll
            for (int n = 0; n < 4; n++)
                acc[m][n] = __builtin_amdgcn_mfma_f32_16x16x32_bf16(af[m], bf[n], acc[m][n], 0, 0, 0);
        __syncthreads();
    }

    if (MODE == 0) {
        #pragma unroll
        for (int n = 0; n < 4; n++) {
            int col = bcol + wc*64 + n*16 + c;
            int t = col >> 10, h = (col >> 6) & 15, d = col & 63;
            short* dst = (t == 0) ? qb : (t == 1) ? kb : vb;
            #pragma unroll
            for (int m = 0; m < 4; m++) {
                #pragma unroll
                for (int j = 0; j < 4; j++) {
                    int row = brow + wr*64 + m*16 + g*4 + j;
                    int bi = row >> 11, ni = row & (SEQ-1);
                    dst[(((size_t)(bi*HEADS + h))*SEQ + ni)*HD + d] = f2bf(acc[m][n][j]);
                }
            }
        }
    } else {
        #pragma unroll
        for (int n = 0; n < 4; n++) {
            int col = bcol + wc*64 + n*16 + c;
            float bv = bias[col];
            #pragma unroll
            for (int m = 0; m < 4; m++) {
                #pragma unroll
                for (int j = 0; j < 4; j++) {
                    int row = brow + wr*64 + m*16 + g*4 + j;
                    out[(size_t)row*DIM + col] = acc[m][n][j] + bv;
                }
            }
        }
    }
}

// ---------------------------------------------------------------------------
// LayerNorm over head_dim=64 for q and k. q gets D^-0.5 * log2(e) folded in.
// ---------------------------------------------------------------------------
__global__ __launch_bounds__(256) void ln_qk(
    short* __restrict__ qb, short* __restrict__ kb,
    const float* __restrict__ qg, const float* __restrict__ qbeta,
    const float* __restrict__ kg, const float* __restrict__ kbeta)
{
    const int gw = blockIdx.x * 4 + (threadIdx.x >> 6);
    const int lane = threadIdx.x & 63;
    const int per = BATCH*HEADS*SEQ;
    const int which = gw >= per;
    const int row = which ? gw - per : gw;
    short* buf = which ? kb : qb;
    const float* gamma = which ? kg : qg;
    const float* beta  = which ? kbeta : qbeta;
    const float scale  = which ? 1.0f : (0.125f * 1.44269504088896340736f);

    short* p = buf + (size_t)row * HD;
    float v = bf2f(p[lane]);
    float s = v;
    #pragma unroll
    for (int m = 32; m; m >>= 1) s += __shfl_xor(s, m);
    float mu = s * (1.0f/64.0f);
    float d = v - mu;
    float vs = d * d;
    #pragma unroll
    for (int m = 32; m; m >>= 1) vs += __shfl_xor(vs, m);
    float rstd = rsqrtf(vs * (1.0f/64.0f) + EPS);
    p[lane] = f2bf((d * rstd * gamma[lane] + beta[lane]) * scale);
}

// ---------------------------------------------------------------------------
// V transpose: [B,H,N,D] -> [B,H,D,N] via LDS, coalesced both sides.
// ---------------------------------------------------------------------------
__global__ __launch_bounds__(256) void vtrans(
    const short* __restrict__ vin, short* __restrict__ vt)
{
    constexpr int LT = 72;
    alignas(16) __shared__ short T[64*LT];
    const int bh = blockIdx.x, n0 = blockIdx.y * 64;
    const int t = threadIdx.x;
    const int r = t >> 2, cq = (t & 3) * 16;
    const short* src = vin + ((size_t)bh*SEQ + n0 + r)*HD + cq;
    *(s16x8*)&T[r*LT + cq]     = *(const s16x8*)src;
    *(s16x8*)&T[r*LT + cq + 8] = *(const s16x8*)(src + 8);
    __syncthreads();
    const int d = t >> 2, nq = (t & 3) * 16;
    s16x8 a, b;
    #pragma unroll
    for (int e = 0; e < 8; e++) { a[e] = T[(nq+e)*LT + d]; b[e] = T[(nq+8+e)*LT + d]; }
    short* dst = vt + ((size_t)bh*HD + d)*SEQ + n0 + nq;
    *(s16x8*)dst       = a;
    *(s16x8*)(dst + 8) = b;
}

// ---------------------------------------------------------------------------
// Flash attention, swapped-operand 32x32 MFMA, register software pipeline:
// issue cur-tile V loads + next-tile K loads before compute; latency hides
// under S-MFMA + softmax. No LDS, no barriers.
// ---------------------------------------------------------------------------
__global__ __launch_bounds__(256) void attn_kernel(
    const short* __restrict__ qbuf, const short* __restrict__ kbuf,
    const short* __restrict__ vtbuf, float* __restrict__ aout)
{
    const int bh = blockIdx.x;
    const int wave = threadIdx.x >> 6, lane = threadIdx.x & 63;
    const int l31 = lane & 31, hi = lane >> 5;
    const int q0 = (blockIdx.y * 4 + wave) * 32;
    const size_t base = (size_t)bh * SEQ * HD;
    const short* Q  = qbuf  + base;
    const short* K  = kbuf  + base;
    const short* VT = vtbuf + base;                // [HD][SEQ]

    s16x8 qf[4];
    const short* qrow = Q + (size_t)(q0 + l31)*HD + 8*hi;
    #pragma unroll
    for (int ks = 0; ks < 4; ks++) qf[ks] = *(const s16x8*)(qrow + 16*ks);

    f32x16 o0 = {}, o1 = {};
    float m = -1e30f, l = 0.f;

    const short* kbase = K  + (size_t)l31*HD  + 8*hi;
    const short* vbase = VT + (size_t)l31*SEQ + 8*hi;

    // prologue: K fragments for tile 0
    s16x8 kc[8];
    #pragma unroll
    for (int ks = 0; ks < 4; ks++) {
        kc[ks]   = *(const s16x8*)(kbase + 16*ks);
        kc[4+ks] = *(const s16x8*)(kbase + 32*HD + 16*ks);
    }

    for (int kt = 0; kt < SEQ; kt += 64) {
        // issue current-tile V loads (used after softmax) and next-tile K loads
        s16x8 vc[8], kn[8];
        #pragma unroll
        for (int ks = 0; ks < 4; ks++) {
            vc[ks]   = *(const s16x8*)(vbase + kt + 16*ks);
            vc[4+ks] = *(const s16x8*)(vbase + 32*SEQ + kt + 16*ks);
        }
        const int ktn = (kt + 64) & (SEQ-1);       // wraps on last iter (harmless)
        const short* kbn = kbase + (size_t)ktn*HD;
        #pragma unroll
        for (int ks = 0; ks < 4; ks++) {
            kn[ks]   = *(const s16x8*)(kbn + 16*ks);
            kn[4+ks] = *(const s16x8*)(kbn + 32*HD + 16*ks);
        }
        __builtin_amdgcn_sched_barrier(0);

        // S^T = K_tile * Q  (two 32x32 fragments)
        f32x16 s0 = {}, s1 = {};
        __builtin_amdgcn_s_setprio(1);
        #pragma unroll
        for (int ks = 0; ks < 4; ks++) {
            s0 = MFMA32(kc[ks],   qf[ks], s0);
            s1 = MFMA32(kc[4+ks], qf[ks], s1);
        }
        __builtin_amdgcn_s_setprio(0);

        // lane-local softmax for q = q0+l31
        float pmax;
        {
            float t[16];
            #pragma unroll
            for (int i = 0; i < 16; i++) t[i] = fmaxf(s0[i], s1[i]);
            #pragma unroll
            for (int st = 8; st > 0; st >>= 1)
                #pragma unroll
                for (int i = 0; i < st; i++) t[i] = fmaxf(t[i], t[i+st]);
            pmax = t[0];
        }
        pmax = fmaxf(pmax, __shfl_xor(pmax, 32));
        float mn = fmaxf(m, pmax);
        float corr = exp2f(m - mn);
        #pragma unroll
        for (int i = 0; i < 16; i++) {
            s0[i] = exp2f(s0[i] - mn);
            s1[i] = exp2f(s1[i] - mn);
        }
        float rs;
        {
            float t[16];
            #pragma unroll
            for (int i = 0; i < 16; i++) t[i] = s0[i] + s1[i];
            #pragma unroll
            for (int st = 8; st > 0; st >>= 1)
                #pragma unroll
                for (int i = 0; i < st; i++) t[i] += t[i+st];
            rs = t[0];
        }
        rs += __shfl_xor(rs, 32);
        l = l*corr + rs;
        m = mn;
        #pragma unroll
        for (int i = 0; i < 16; i++) { o0[i] *= corr; o1[i] *= corr; }

        // P -> bf16 A-fragments via cvt_pk + permlane32_swap (T12)
        s16x8 pa[4];
        #pragma unroll
        for (int ks = 0; ks < 4; ks++) {
            const int rb = 8*(ks & 1);
            unsigned A0, A1, B0, B1;
            if (ks < 2) {
                A0 = cvtpk(s0[rb+0], s0[rb+1]); A1 = cvtpk(s0[rb+2], s0[rb+3]);
                B0 = cvtpk(s0[rb+4], s0[rb+5]); B1 = cvtpk(s0[rb+6], s0[rb+7]);
            } else {
                A0 = cvtpk(s1[rb+0], s1[rb+1]); A1 = cvtpk(s1[rb+2], s1[rb+3]);
                B0 = cvtpk(s1[rb+4], s1[rb+5]); B1 = cvtpk(s1[rb+6], s1[rb+7]);
            }
            asm volatile("v_permlane32_swap_b32 %0, %1" : "+v"(A0), "+v"(B0));
            asm volatile("v_permlane32_swap_b32 %0, %1" : "+v"(A1), "+v"(B1));
            union { s16x8 v; unsigned u[4]; } w;
            w.u[0] = A0; w.u[1] = A1; w.u[2] = B0; w.u[3] = B1;
            pa[ks] = w.v;
        }

        // O^T += V^T * P
        __builtin_amdgcn_s_setprio(1);
        #pragma unroll
        for (int ks = 0; ks < 4; ks++) {
            o0 = MFMA32(vc[ks],   pa[ks], o0);
            o1 = MFMA32(vc[4+ks], pa[ks], o1);
        }
        __builtin_amdgcn_s_setprio(0);

        #pragma unroll
        for (int i = 0; i < 8; i++) kc[i] = kn[i];
    }

    // epilogue: lane writes its own q row
    const int b = bh >> 4, h = bh & 15;
    const float invl = 1.0f / l;
    float* dst = aout + ((size_t)(b*SEQ + q0 + l31))*DIM + h*HD;
    #pragma unroll
    for (int t = 0; t < 4; t++) {
        f32x4 w0, w1;
        #pragma unroll
        for (int j = 0; j < 4; j++) { w0[j] = o0[4*t + j]*invl; w1[j] = o1[4*t + j]*invl; }
        *(f32x4*)(dst + 8*t + 4*hi)      = w0;
        *(f32x4*)(dst + 32 + 8*t + 4*hi) = w1;
    }
}

// ---------------------------------------------------------------------------
extern "C" void kernel_launch(void* const* d_in, const int* in_sizes, int n_in,
                              void* d_out, int out_size, void* d_ws, size_t ws_size,
                              hipStream_t stream)
{
    const float* x     = (const float*)d_in[0];
    const float* Wqkv  = (const float*)d_in[1];
    const float* qg    = (const float*)d_in[2];
    const float* qbeta = (const float*)d_in[3];
    const float* kg    = (const float*)d_in[4];
    const float* kbeta = (const float*)d_in[5];
    const float* Wproj = (const float*)d_in[6];
    const float* bproj = (const float*)d_in[7];
    float* out = (float*)d_out;

    char* ws = (char*)d_ws;
    const size_t qkv_b = (size_t)BATCH*HEADS*SEQ*HD*2;     // 8 MB per tensor
    short* q    = (short*)(ws);
    short* k    = (short*)(ws + qkv_b);
    short* vt   = (short*)(ws + 2*qkv_b);                  // V^T [B,H,D,N]
    short* vrow = (short*)(ws + 3*qkv_b);                  // aliases aout start (dead before attn)
    float* aout = (float*)(ws + 3*qkv_b);                  // [ROWS][DIM] fp32, 16 MB

    gemm_kernel<0><<<dim3(3*DIM/BN, ROWS/BM), 256, 0, stream>>>(
        x, Wqkv, nullptr, q, k, vrow, nullptr);

    ln_qk<<<dim3(2*BATCH*HEADS*SEQ/4), 256, 0, stream>>>(q, k, qg, qbeta, kg, kbeta);

    vtrans<<<dim3(BATCH*HEADS, SEQ/64), 256, 0, stream>>>(vrow, vt);

    attn_kernel<<<dim3(BATCH*HEADS, SEQ/128), 256, 0, stream>>>(q, k, vt, aout);

    gemm_kernel<1><<<dim3(DIM/BN, ROWS/BM), 256, 0, stream>>>(
        aout, Wproj, bproj, nullptr, nullptr, nullptr, out);
}

// Round 4
// 201.547 us; speedup vs baseline: 1.5378x; 1.2670x over previous
//
#include <hip/hip_runtime.h>

#define DIM 1024
#define HEADS 16
#define HD 64
#define BATCH 2
#define SEQ 2048
#define ROWS (BATCH*SEQ)          // 4096
#define EPS 1e-6f

typedef float f32x4  __attribute__((ext_vector_type(4)));
typedef float f32x16 __attribute__((ext_vector_type(16)));
typedef short s16x8  __attribute__((ext_vector_type(8)));

static __device__ __forceinline__ short f2bf(float f) {
    union { float f; unsigned u; } x; x.f = f;
    unsigned r = x.u + 0x7FFFu + ((x.u >> 16) & 1u);
    return (short)(r >> 16);
}
static __device__ __forceinline__ float bf2f(short s) {
    union { unsigned u; float f; } x; x.u = ((unsigned)(unsigned short)s) << 16;
    return x.f;
}
static __device__ __forceinline__ s16x8 pack8(float4 lo, float4 hi) {
    s16x8 r;
    r[0]=f2bf(lo.x); r[1]=f2bf(lo.y); r[2]=f2bf(lo.z); r[3]=f2bf(lo.w);
    r[4]=f2bf(hi.x); r[5]=f2bf(hi.y); r[6]=f2bf(hi.z); r[7]=f2bf(hi.w);
    return r;
}
static __device__ __forceinline__ unsigned cvtpk(float a, float b) {
    unsigned r;
    asm("v_cvt_pk_bf16_f32 %0, %1, %2" : "=v"(r) : "v"(a), "v"(b));
    return r;
}

#define MFMA32(A,B,C) __builtin_amdgcn_mfma_f32_32x32x16_bf16(A, B, C, 0, 0, 0)

// ---------------------------------------------------------------------------
// GEMM: C[M][Ncols] = A[M][K] * W[Ncols][K]^T   (A,W fp32; compute bf16 MFMA)
// MODE 0: epilogue scatters bf16 q/k/v to [B,H,N,D] (all row-major, coalesced)
// MODE 1: epilogue adds bias and writes fp32 to out (proj gemm)
// ---------------------------------------------------------------------------
#define BM 128
#define BN 128
#define BK 32
#define LDT 40   // LDS row stride in shorts

template<int MODE>
__global__ __launch_bounds__(256) void gemm_kernel(
    const float* __restrict__ A, const float* __restrict__ W,
    const float* __restrict__ bias,
    short* __restrict__ qb, short* __restrict__ kb, short* __restrict__ vb,
    float* __restrict__ out)
{
    alignas(16) __shared__ short As[BM*LDT];
    alignas(16) __shared__ short Bs[BN*LDT];
    const int tid  = threadIdx.x;
    const int lane = tid & 63, wave = tid >> 6;
    const int wr = wave >> 1, wc = wave & 1;
    const int c = lane & 15, g = lane >> 4;
    const int brow = blockIdx.y * BM, bcol = blockIdx.x * BN;
    const int sr = tid >> 1, sk = (tid & 1) * 16;

    f32x4 acc[4][4] = {};

    for (int k0 = 0; k0 < DIM; k0 += BK) {
        const float4* pa = (const float4*)(A + (size_t)(brow + sr) * DIM + k0 + sk);
        const float4* pb = (const float4*)(W + (size_t)(bcol + sr) * DIM + k0 + sk);
        float4 a0 = pa[0], a1 = pa[1], a2 = pa[2], a3 = pa[3];
        float4 b0 = pb[0], b1 = pb[1], b2 = pb[2], b3 = pb[3];
        *(s16x8*)&As[sr*LDT + sk]     = pack8(a0, a1);
        *(s16x8*)&As[sr*LDT + sk + 8] = pack8(a2, a3);
        *(s16x8*)&Bs[sr*LDT + sk]     = pack8(b0, b1);
        *(s16x8*)&Bs[sr*LDT + sk + 8] = pack8(b2, b3);
        __syncthreads();

        s16x8 af[4], bf[4];
        #pragma unroll
        for (int m = 0; m < 4; m++)
            af[m] = *(const s16x8*)&As[(wr*64 + m*16 + c)*LDT + g*8];
        #pragma unroll
        for (int n = 0; n < 4; n++)
            bf[n] = *(const s16x8*)&Bs[(wc*64 + n*16 + c)*LDT + g*8];
        #pragma unroll
        for (int m = 0; m < 4; m++)
            #pragma unroll
            for (int n = 0; n < 4; n++)
                acc[m][n] = __builtin_amdgcn_mfma_f32_16x16x32_bf16(af[m], bf[n], acc[m][n], 0, 0, 0);
        __syncthreads();
    }

    if (MODE == 0) {
        #pragma unroll
        for (int n = 0; n < 4; n++) {
            int col = bcol + wc*64 + n*16 + c;
            int t = col >> 10, h = (col >> 6) & 15, d = col & 63;
            short* dst = (t == 0) ? qb : (t == 1) ? kb : vb;
            #pragma unroll
            for (int m = 0; m < 4; m++) {
                #pragma unroll
                for (int j = 0; j < 4; j++) {
                    int row = brow + wr*64 + m*16 + g*4 + j;
                    int bi = row >> 11, ni = row & (SEQ-1);
                    dst[(((size_t)(bi*HEADS + h))*SEQ + ni)*HD + d] = f2bf(acc[m][n][j]);
                }
            }
        }
    } else {
        #pragma unroll
        for (int n = 0; n < 4; n++) {
            int col = bcol + wc*64 + n*16 + c;
            float bv = bias[col];
            #pragma unroll
            for (int m = 0; m < 4; m++) {
                #pragma unroll
                for (int j = 0; j < 4; j++) {
                    int row = brow + wr*64 + m*16 + g*4 + j;
                    out[(size_t)row*DIM + col] = acc[m][n][j] + bv;
                }
            }
        }
    }
}

// ---------------------------------------------------------------------------
// LayerNorm over head_dim=64 for q and k. q gets D^-0.5 * log2(e) folded in.
// ---------------------------------------------------------------------------
__global__ __launch_bounds__(256) void ln_qk(
    short* __restrict__ qb, short* __restrict__ kb,
    const float* __restrict__ qg, const float* __restrict__ qbeta,
    const float* __restrict__ kg, const float* __restrict__ kbeta)
{
    const int gw = blockIdx.x * 4 + (threadIdx.x >> 6);
    const int lane = threadIdx.x & 63;
    const int per = BATCH*HEADS*SEQ;
    const int which = gw >= per;
    const int row = which ? gw - per : gw;
    short* buf = which ? kb : qb;
    const float* gamma = which ? kg : qg;
    const float* beta  = which ? kbeta : qbeta;
    const float scale  = which ? 1.0f : (0.125f * 1.44269504088896340736f);

    short* p = buf + (size_t)row * HD;
    float v = bf2f(p[lane]);
    float s = v;
    #pragma unroll
    for (int m = 32; m; m >>= 1) s += __shfl_xor(s, m);
    float mu = s * (1.0f/64.0f);
    float d = v - mu;
    float vs = d * d;
    #pragma unroll
    for (int m = 32; m; m >>= 1) vs += __shfl_xor(vs, m);
    float rstd = rsqrtf(vs * (1.0f/64.0f) + EPS);
    p[lane] = f2bf((d * rstd * gamma[lane] + beta[lane]) * scale);
}

// ---------------------------------------------------------------------------
// V transpose: [B,H,N,D] -> [B,H,D,N] via LDS, coalesced both sides.
// ---------------------------------------------------------------------------
__global__ __launch_bounds__(256) void vtrans(
    const short* __restrict__ vin, short* __restrict__ vt)
{
    constexpr int LT = 72;
    alignas(16) __shared__ short T[64*LT];
    const int bh = blockIdx.x, n0 = blockIdx.y * 64;
    const int t = threadIdx.x;
    const int r = t >> 2, cq = (t & 3) * 16;
    const short* src = vin + ((size_t)bh*SEQ + n0 + r)*HD + cq;
    *(s16x8*)&T[r*LT + cq]     = *(const s16x8*)src;
    *(s16x8*)&T[r*LT + cq + 8] = *(const s16x8*)(src + 8);
    __syncthreads();
    const int d = t >> 2, nq = (t & 3) * 16;
    s16x8 a, b;
    #pragma unroll
    for (int e = 0; e < 8; e++) { a[e] = T[(nq+e)*LT + d]; b[e] = T[(nq+8+e)*LT + d]; }
    short* dst = vt + ((size_t)bh*HD + d)*SEQ + n0 + nq;
    *(s16x8*)dst       = a;
    *(s16x8*)(dst + 8) = b;
}

// ---------------------------------------------------------------------------
// Flash attention, swapped-operand 32x32 MFMA, LDS-staged K/V tiles:
// coalesced 1KB staging loads, XOR-swizzled LDS (write+read), double buffer,
// async-stage split (loads early, ds_write after compute), 1 barrier/tile.
// ---------------------------------------------------------------------------
__global__ __launch_bounds__(256) void attn_kernel(
    const short* __restrict__ qbuf, const short* __restrict__ kbuf,
    const short* __restrict__ vtbuf, float* __restrict__ aout)
{
    alignas(16) __shared__ short Ks[2][64*64];   // [buf][key][ch], swizzled
    alignas(16) __shared__ short Vs[2][64*64];   // [buf][ch][key], swizzled

    const int bh = blockIdx.x;
    const int tid = threadIdx.x;
    const int wave = tid >> 6, lane = tid & 63;
    const int l31 = lane & 31, hi = lane >> 5;
    const int q0 = (blockIdx.y * 4 + wave) * 32;
    const size_t base = (size_t)bh * SEQ * HD;
    const short* Q  = qbuf  + base;
    const short* K  = kbuf  + base;
    const short* VT = vtbuf + base;               // [HD][SEQ]

    // staging: thread t owns 32B of the K tile and 32B of the V tile
    const int srow = tid >> 2;                    // 0..63
    const int scol = (tid & 3) * 16;              // shorts
    const int sd0 = (srow*128 + scol*2) ^ ((srow & 7) << 4);
    const int sd1 = (srow*128 + scol*2 + 16) ^ ((srow & 7) << 4);

    // Q fragments (one-time)
    s16x8 qf[4];
    const short* qrow = Q + (size_t)(q0 + l31)*HD + 8*hi;
    #pragma unroll
    for (int ks = 0; ks < 4; ks++) qf[ks] = *(const s16x8*)(qrow + 16*ks);

    // fragment read byte-offsets: rows l31 / 32+l31, col 16ks+8hi shorts
    int roff[8];
    #pragma unroll
    for (int ks = 0; ks < 4; ks++) {
        roff[ks]   = (l31*128      + 32*ks + 16*hi) ^ ((l31 & 7) << 4);
        roff[4+ks] = ((32+l31)*128 + 32*ks + 16*hi) ^ ((l31 & 7) << 4);
    }

    f32x16 o0 = {}, o1 = {};
    float m = -1e30f, l = 0.f;

    // prologue: stage tile 0 into buffer 0
    {
        const short* kg = K  + (size_t)srow*HD + scol;        // contiguous 8KB tile
        const short* vg = VT + (size_t)srow*SEQ + scol;
        s16x8 ka = *(const s16x8*)kg, kb2 = *(const s16x8*)(kg + 8);
        s16x8 va = *(const s16x8*)vg, vb2 = *(const s16x8*)(vg + 8);
        *(s16x8*)((char*)Ks[0] + sd0) = ka;
        *(s16x8*)((char*)Ks[0] + sd1) = kb2;
        *(s16x8*)((char*)Vs[0] + sd0) = va;
        *(s16x8*)((char*)Vs[0] + sd1) = vb2;
    }
    __syncthreads();

    int cur = 0;
    for (int kt = 0; kt < SEQ; kt += 64) {
        // async-stage: issue NEXT tile's global loads now (land before barrier)
        const int ktn = (kt + 64) & (SEQ - 1);                // wraps; harmless
        const short* kg = K  + (size_t)(ktn + srow)*HD + scol;
        const short* vg = VT + (size_t)srow*SEQ + ktn + scol;
        s16x8 ka = *(const s16x8*)kg, kb2 = *(const s16x8*)(kg + 8);
        s16x8 va = *(const s16x8*)vg, vb2 = *(const s16x8*)(vg + 8);

        const char* kl = (const char*)Ks[cur];
        const char* vl = (const char*)Vs[cur];

        // S^T = K_tile * Q
        f32x16 s0 = {}, s1 = {};
        __builtin_amdgcn_s_setprio(1);
        #pragma unroll
        for (int ks = 0; ks < 4; ks++) {
            s16x8 kf0 = *(const s16x8*)(kl + roff[ks]);
            s16x8 kf1 = *(const s16x8*)(kl + roff[4+ks]);
            s0 = MFMA32(kf0, qf[ks], s0);
            s1 = MFMA32(kf1, qf[ks], s1);
        }
        __builtin_amdgcn_s_setprio(0);

        // lane-local softmax for q = q0+l31 (explicit trees, const indices)
        float t8[8];
        #pragma unroll
        for (int i = 0; i < 8; i++) t8[i] = fmaxf(fmaxf(s0[i], s0[i+8]), fmaxf(s1[i], s1[i+8]));
        #pragma unroll
        for (int i = 0; i < 4; i++) t8[i] = fmaxf(t8[i], t8[i+4]);
        float pmax = fmaxf(fmaxf(t8[0], t8[2]), fmaxf(t8[1], t8[3]));
        pmax = fmaxf(pmax, __shfl_xor(pmax, 32));

        // defer-max (T13): rescale only if some row's max grew past threshold
        if (!__all(pmax - m <= 8.0f)) {
            float mn = fmaxf(m, pmax);
            float corr = exp2f(m - mn);
            #pragma unroll
            for (int i = 0; i < 16; i++) { o0[i] *= corr; o1[i] *= corr; }
            l *= corr;
            m = mn;
        }
        #pragma unroll
        for (int i = 0; i < 16; i++) {
            s0[i] = exp2f(s0[i] - m);
            s1[i] = exp2f(s1[i] - m);
        }
        float a8[8];
        #pragma unroll
        for (int i = 0; i < 8; i++) a8[i] = (s0[i] + s0[i+8]) + (s1[i] + s1[i+8]);
        #pragma unroll
        for (int i = 0; i < 4; i++) a8[i] += a8[i+4];
        float rs = (a8[0] + a8[2]) + (a8[1] + a8[3]);
        rs += __shfl_xor(rs, 32);
        l += rs;

        // P -> bf16 A-fragments via cvt_pk + permlane32_swap (T12)
        s16x8 pa[4];
        #pragma unroll
        for (int ks = 0; ks < 4; ks++) {
            const int rb = 8*(ks & 1);
            unsigned A0, A1, B0, B1;
            if (ks < 2) {
                A0 = cvtpk(s0[rb+0], s0[rb+1]); A1 = cvtpk(s0[rb+2], s0[rb+3]);
                B0 = cvtpk(s0[rb+4], s0[rb+5]); B1 = cvtpk(s0[rb+6], s0[rb+7]);
            } else {
                A0 = cvtpk(s1[rb+0], s1[rb+1]); A1 = cvtpk(s1[rb+2], s1[rb+3]);
                B0 = cvtpk(s1[rb+4], s1[rb+5]); B1 = cvtpk(s1[rb+6], s1[rb+7]);
            }
            asm volatile("v_permlane32_swap_b32 %0, %1" : "+v"(A0), "+v"(B0));
            asm volatile("v_permlane32_swap_b32 %0, %1" : "+v"(A1), "+v"(B1));
            union { s16x8 v; unsigned u[4]; } w;
            w.u[0] = A0; w.u[1] = A1; w.u[2] = B0; w.u[3] = B1;
            pa[ks] = w.v;
        }

        // O^T += V^T * P
        __builtin_amdgcn_s_setprio(1);
        #pragma unroll
        for (int ks = 0; ks < 4; ks++) {
            s16x8 vf0 = *(const s16x8*)(vl + roff[ks]);
            s16x8 vf1 = *(const s16x8*)(vl + roff[4+ks]);
            o0 = MFMA32(vf0, pa[ks], o0);
            o1 = MFMA32(vf1, pa[ks], o1);
        }
        __builtin_amdgcn_s_setprio(0);

        // write next tile into the other buffer, then one barrier
        const int nxt = cur ^ 1;
        *(s16x8*)((char*)Ks[nxt] + sd0) = ka;
        *(s16x8*)((char*)Ks[nxt] + sd1) = kb2;
        *(s16x8*)((char*)Vs[nxt] + sd0) = va;
        *(s16x8*)((char*)Vs[nxt] + sd1) = vb2;
        __syncthreads();
        cur = nxt;
    }

    // epilogue: lane writes its own q row
    const int b = bh >> 4, h = bh & 15;
    const float invl = 1.0f / l;
    float* dst = aout + ((size_t)(b*SEQ + q0 + l31))*DIM + h*HD;
    #pragma unroll
    for (int t = 0; t < 4; t++) {
        f32x4 w0, w1;
        #pragma unroll
        for (int j = 0; j < 4; j++) { w0[j] = o0[4*t + j]*invl; w1[j] = o1[4*t + j]*invl; }
        *(f32x4*)(dst + 8*t + 4*hi)      = w0;
        *(f32x4*)(dst + 32 + 8*t + 4*hi) = w1;
    }
}

// ---------------------------------------------------------------------------
extern "C" void kernel_launch(void* const* d_in, const int* in_sizes, int n_in,
                              void* d_out, int out_size, void* d_ws, size_t ws_size,
                              hipStream_t stream)
{
    const float* x     = (const float*)d_in[0];
    const float* Wqkv  = (const float*)d_in[1];
    const float* qg    = (const float*)d_in[2];
    const float* qbeta = (const float*)d_in[3];
    const float* kg    = (const float*)d_in[4];
    const float* kbeta = (const float*)d_in[5];
    const float* Wproj = (const float*)d_in[6];
    const float* bproj = (const float*)d_in[7];
    float* out = (float*)d_out;

    char* ws = (char*)d_ws;
    const size_t qkv_b = (size_t)BATCH*HEADS*SEQ*HD*2;     // 8 MB per tensor
    short* q    = (short*)(ws);
    short* k    = (short*)(ws + qkv_b);
    short* vt   = (short*)(ws + 2*qkv_b);                  // V^T [B,H,D,N]
    short* vrow = (short*)(ws + 3*qkv_b);                  // aliases aout (dead before attn)
    float* aout = (float*)(ws + 3*qkv_b);                  // [ROWS][DIM] fp32

    gemm_kernel<0><<<dim3(3*DIM/BN, ROWS/BM), 256, 0, stream>>>(
        x, Wqkv, nullptr, q, k, vrow, nullptr);

    ln_qk<<<dim3(2*BATCH*HEADS*SEQ/4), 256, 0, stream>>>(q, k, qg, qbeta, kg, kbeta);

    vtrans<<<dim3(BATCH*HEADS, SEQ/64), 256, 0, stream>>>(vrow, vt);

    attn_kernel<<<dim3(BATCH*HEADS, SEQ/128), 256, 0, stream>>>(q, k, vt, aout);

    gemm_kernel<1><<<dim3(DIM/BN, ROWS/BM), 256, 0, stream>>>(
        aout, Wproj, bproj, nullptr, nullptr, nullptr, out);
}

// Round 5
// 196.899 us; speedup vs baseline: 1.5741x; 1.0236x over previous
//
#include <hip/hip_runtime.h>

#define DIM 1024
#define HEADS 16
#define HD 64
#define BATCH 2
#define SEQ 2048
#define ROWS (BATCH*SEQ)          // 4096
#define EPS 1e-6f

typedef float f32x4  __attribute__((ext_vector_type(4)));
typedef float f32x16 __attribute__((ext_vector_type(16)));
typedef short s16x8  __attribute__((ext_vector_type(8)));

static __device__ __forceinline__ short f2bf(float f) {
    union { float f; unsigned u; } x; x.f = f;
    unsigned r = x.u + 0x7FFFu + ((x.u >> 16) & 1u);
    return (short)(r >> 16);
}
static __device__ __forceinline__ float bf2f(short s) {
    union { unsigned u; float f; } x; x.u = ((unsigned)(unsigned short)s) << 16;
    return x.f;
}
static __device__ __forceinline__ s16x8 pack8(float4 lo, float4 hi) {
    s16x8 r;
    r[0]=f2bf(lo.x); r[1]=f2bf(lo.y); r[2]=f2bf(lo.z); r[3]=f2bf(lo.w);
    r[4]=f2bf(hi.x); r[5]=f2bf(hi.y); r[6]=f2bf(hi.z); r[7]=f2bf(hi.w);
    return r;
}
static __device__ __forceinline__ unsigned cvtpk(float a, float b) {
    unsigned r;
    asm("v_cvt_pk_bf16_f32 %0, %1, %2" : "=v"(r) : "v"(a), "v"(b));
    return r;
}

#define MFMA32(A,B,C) __builtin_amdgcn_mfma_f32_32x32x16_bf16(A, B, C, 0, 0, 0)

// ---------------------------------------------------------------------------
// GEMM: C[M][Ncols] = A[M][K] * W[Ncols][K]^T   (A,W fp32; compute bf16 MFMA)
// MODE 0: epilogue scatters bf16 q/k/v to [B,H,N,D] (all row-major, coalesced)
// MODE 1: epilogue adds bias and writes fp32 to out (proj gemm)
// ---------------------------------------------------------------------------
#define BM 128
#define BN 128
#define BK 32
#define LDT 40   // LDS row stride in shorts

template<int MODE>
__global__ __launch_bounds__(256) void gemm_kernel(
    const float* __restrict__ A, const float* __restrict__ W,
    const float* __restrict__ bias,
    short* __restrict__ qb, short* __restrict__ kb, short* __restrict__ vb,
    float* __restrict__ out)
{
    alignas(16) __shared__ short As[BM*LDT];
    alignas(16) __shared__ short Bs[BN*LDT];
    const int tid  = threadIdx.x;
    const int lane = tid & 63, wave = tid >> 6;
    const int wr = wave >> 1, wc = wave & 1;
    const int c = lane & 15, g = lane >> 4;
    const int brow = blockIdx.y * BM, bcol = blockIdx.x * BN;
    const int sr = tid >> 1, sk = (tid & 1) * 16;

    f32x4 acc[4][4] = {};

    for (int k0 = 0; k0 < DIM; k0 += BK) {
        const float4* pa = (const float4*)(A + (size_t)(brow + sr) * DIM + k0 + sk);
        const float4* pb = (const float4*)(W + (size_t)(bcol + sr) * DIM + k0 + sk);
        float4 a0 = pa[0], a1 = pa[1], a2 = pa[2], a3 = pa[3];
        float4 b0 = pb[0], b1 = pb[1], b2 = pb[2], b3 = pb[3];
        *(s16x8*)&As[sr*LDT + sk]     = pack8(a0, a1);
        *(s16x8*)&As[sr*LDT + sk + 8] = pack8(a2, a3);
        *(s16x8*)&Bs[sr*LDT + sk]     = pack8(b0, b1);
        *(s16x8*)&Bs[sr*LDT + sk + 8] = pack8(b2, b3);
        __syncthreads();

        s16x8 af[4], bf[4];
        #pragma unroll
        for (int m = 0; m < 4; m++)
            af[m] = *(const s16x8*)&As[(wr*64 + m*16 + c)*LDT + g*8];
        #pragma unroll
        for (int n = 0; n < 4; n++)
            bf[n] = *(const s16x8*)&Bs[(wc*64 + n*16 + c)*LDT + g*8];
        #pragma unroll
        for (int m = 0; m < 4; m++)
            #pragma unroll
            for (int n = 0; n < 4; n++)
                acc[m][n] = __builtin_amdgcn_mfma_f32_16x16x32_bf16(af[m], bf[n], acc[m][n], 0, 0, 0);
        __syncthreads();
    }

    if (MODE == 0) {
        #pragma unroll
        for (int n = 0; n < 4; n++) {
            int col = bcol + wc*64 + n*16 + c;
            int t = col >> 10, h = (col >> 6) & 15, d = col & 63;
            short* dst = (t == 0) ? qb : (t == 1) ? kb : vb;
            #pragma unroll
            for (int m = 0; m < 4; m++) {
                #pragma unroll
                for (int j = 0; j < 4; j++) {
                    int row = brow + wr*64 + m*16 + g*4 + j;
                    int bi = row >> 11, ni = row & (SEQ-1);
                    dst[(((size_t)(bi*HEADS + h))*SEQ + ni)*HD + d] = f2bf(acc[m][n][j]);
                }
            }
        }
    } else {
        #pragma unroll
        for (int n = 0; n < 4; n++) {
            int col = bcol + wc*64 + n*16 + c;
            float bv = bias[col];
            #pragma unroll
            for (int m = 0; m < 4; m++) {
                #pragma unroll
                for (int j = 0; j < 4; j++) {
                    int row = brow + wr*64 + m*16 + g*4 + j;
                    out[(size_t)row*DIM + col] = acc[m][n][j] + bv;
                }
            }
        }
    }
}

// ---------------------------------------------------------------------------
// LayerNorm over head_dim=64 for q and k. q gets D^-0.5 * log2(e) folded in.
// ---------------------------------------------------------------------------
__global__ __launch_bounds__(256) void ln_qk(
    short* __restrict__ qb, short* __restrict__ kb,
    const float* __restrict__ qg, const float* __restrict__ qbeta,
    const float* __restrict__ kg, const float* __restrict__ kbeta)
{
    const int gw = blockIdx.x * 4 + (threadIdx.x >> 6);
    const int lane = threadIdx.x & 63;
    const int per = BATCH*HEADS*SEQ;
    const int which = gw >= per;
    const int row = which ? gw - per : gw;
    short* buf = which ? kb : qb;
    const float* gamma = which ? kg : qg;
    const float* beta  = which ? kbeta : qbeta;
    const float scale  = which ? 1.0f : (0.125f * 1.44269504088896340736f);

    short* p = buf + (size_t)row * HD;
    float v = bf2f(p[lane]);
    float s = v;
    #pragma unroll
    for (int m = 32; m; m >>= 1) s += __shfl_xor(s, m);
    float mu = s * (1.0f/64.0f);
    float d = v - mu;
    float vs = d * d;
    #pragma unroll
    for (int m = 32; m; m >>= 1) vs += __shfl_xor(vs, m);
    float rstd = rsqrtf(vs * (1.0f/64.0f) + EPS);
    p[lane] = f2bf((d * rstd * gamma[lane] + beta[lane]) * scale);
}

// ---------------------------------------------------------------------------
// V transpose: [B,H,N,D] -> [B,H,D,N] via LDS, coalesced both sides.
// ---------------------------------------------------------------------------
__global__ __launch_bounds__(256) void vtrans(
    const short* __restrict__ vin, short* __restrict__ vt)
{
    constexpr int LT = 72;
    alignas(16) __shared__ short T[64*LT];
    const int bh = blockIdx.x, n0 = blockIdx.y * 64;
    const int t = threadIdx.x;
    const int r = t >> 2, cq = (t & 3) * 16;
    const short* src = vin + ((size_t)bh*SEQ + n0 + r)*HD + cq;
    *(s16x8*)&T[r*LT + cq]     = *(const s16x8*)src;
    *(s16x8*)&T[r*LT + cq + 8] = *(const s16x8*)(src + 8);
    __syncthreads();
    const int d = t >> 2, nq = (t & 3) * 16;
    s16x8 a, b;
    #pragma unroll
    for (int e = 0; e < 8; e++) { a[e] = T[(nq+e)*LT + d]; b[e] = T[(nq+8+e)*LT + d]; }
    short* dst = vt + ((size_t)bh*HD + d)*SEQ + n0 + nq;
    *(s16x8*)dst       = a;
    *(s16x8*)(dst + 8) = b;
}

// ---------------------------------------------------------------------------
// Flash attention, in-block split-K: 8 waves (2 K-halves x 4 q-subtiles).
// Each half: LDS-staged swizzled K/V tiles, double-buffered, 1 barrier/tile.
// Final flash-merge of the two halves through LDS.
// ---------------------------------------------------------------------------
__global__ __launch_bounds__(512, 4) void attn_kernel(
    const short* __restrict__ qbuf, const short* __restrict__ kbuf,
    const short* __restrict__ vtbuf, float* __restrict__ aout)
{
    alignas(16) __shared__ short Ks[2][2][64*64];   // [half][buf][key][ch]
    alignas(16) __shared__ short Vs[2][2][64*64];   // [half][buf][ch][key]

    const int bh = blockIdx.x;
    const int tid = threadIdx.x;
    const int wave = tid >> 6, lane = tid & 63;
    const int half = wave >> 2, w4 = wave & 3;
    const int l31 = lane & 31, hi = lane >> 5;
    const int q0 = (blockIdx.y * 4 + w4) * 32;
    const size_t base = (size_t)bh * SEQ * HD;
    const short* Q  = qbuf  + base;
    const short* K  = kbuf  + base;
    const short* VT = vtbuf + base;                 // [HD][SEQ]
    const int kt0 = half * (SEQ/2);

    // staging: 256 threads per half, each owns 32B of K tile and V tile
    const int t2 = tid & 255;
    const int srow = t2 >> 2;                       // 0..63
    const int scol = (t2 & 3) * 16;                 // shorts
    const int sd0 = (srow*128 + scol*2) ^ ((srow & 7) << 4);
    const int sd1 = sd0 ^ 16;

    // Q fragments (one-time)
    s16x8 qf[4];
    const short* qrow = Q + (size_t)(q0 + l31)*HD + 8*hi;
    #pragma unroll
    for (int ks = 0; ks < 4; ks++) qf[ks] = *(const s16x8*)(qrow + 16*ks);

    // fragment read byte-offsets: rows l31 / 32+l31, col 16ks+8hi shorts
    int roff[8];
    #pragma unroll
    for (int ks = 0; ks < 4; ks++) {
        roff[ks]   = (l31*128      + 32*ks + 16*hi) ^ ((l31 & 7) << 4);
        roff[4+ks] = ((32+l31)*128 + 32*ks + 16*hi) ^ ((l31 & 7) << 4);
    }

    f32x16 o0 = {}, o1 = {};
    float m = -1e30f, l = 0.f;

    // prologue: stage this half's tile 0 into buffer 0
    {
        const short* kg = K  + (size_t)(kt0 + srow)*HD + scol;
        const short* vg = VT + (size_t)srow*SEQ + kt0 + scol;
        s16x8 ka = *(const s16x8*)kg, kb2 = *(const s16x8*)(kg + 8);
        s16x8 va = *(const s16x8*)vg, vb2 = *(const s16x8*)(vg + 8);
        *(s16x8*)((char*)Ks[half][0] + sd0) = ka;
        *(s16x8*)((char*)Ks[half][0] + sd1) = kb2;
        *(s16x8*)((char*)Vs[half][0] + sd0) = va;
        *(s16x8*)((char*)Vs[half][0] + sd1) = vb2;
    }
    __syncthreads();

    int cur = 0;
    for (int i = 0; i < 16; i++) {
        // async-stage: issue NEXT tile's global loads now
        const int ktn = kt0 + ((i + 1) & 15) * 64;
        const short* kg = K  + (size_t)(ktn + srow)*HD + scol;
        const short* vg = VT + (size_t)srow*SEQ + ktn + scol;
        s16x8 ka = *(const s16x8*)kg, kb2 = *(const s16x8*)(kg + 8);
        s16x8 va = *(const s16x8*)vg, vb2 = *(const s16x8*)(vg + 8);

        const char* kl = (const char*)Ks[half][cur];
        const char* vl = (const char*)Vs[half][cur];

        // S^T = K_tile * Q
        f32x16 s0 = {}, s1 = {};
        __builtin_amdgcn_s_setprio(1);
        #pragma unroll
        for (int ks = 0; ks < 4; ks++) {
            s16x8 kf0 = *(const s16x8*)(kl + roff[ks]);
            s16x8 kf1 = *(const s16x8*)(kl + roff[4+ks]);
            s0 = MFMA32(kf0, qf[ks], s0);
            s1 = MFMA32(kf1, qf[ks], s1);
        }
        __builtin_amdgcn_s_setprio(0);

        // lane-local softmax for q = q0+l31
        float t8[8];
        #pragma unroll
        for (int i2 = 0; i2 < 8; i2++) t8[i2] = fmaxf(fmaxf(s0[i2], s0[i2+8]), fmaxf(s1[i2], s1[i2+8]));
        #pragma unroll
        for (int i2 = 0; i2 < 4; i2++) t8[i2] = fmaxf(t8[i2], t8[i2+4]);
        float pmax = fmaxf(fmaxf(t8[0], t8[2]), fmaxf(t8[1], t8[3]));
        pmax = fmaxf(pmax, __shfl_xor(pmax, 32));

        // defer-max (T13)
        if (!__all(pmax - m <= 8.0f)) {
            float mn = fmaxf(m, pmax);
            float corr = exp2f(m - mn);
            #pragma unroll
            for (int i2 = 0; i2 < 16; i2++) { o0[i2] *= corr; o1[i2] *= corr; }
            l *= corr;
            m = mn;
        }
        #pragma unroll
        for (int i2 = 0; i2 < 16; i2++) {
            s0[i2] = exp2f(s0[i2] - m);
            s1[i2] = exp2f(s1[i2] - m);
        }
        float a8[8];
        #pragma unroll
        for (int i2 = 0; i2 < 8; i2++) a8[i2] = (s0[i2] + s0[i2+8]) + (s1[i2] + s1[i2+8]);
        #pragma unroll
        for (int i2 = 0; i2 < 4; i2++) a8[i2] += a8[i2+4];
        float rs = (a8[0] + a8[2]) + (a8[1] + a8[3]);
        rs += __shfl_xor(rs, 32);
        l += rs;

        // P -> bf16 A-fragments via cvt_pk + permlane32_swap (T12)
        s16x8 pa[4];
        #pragma unroll
        for (int ks = 0; ks < 4; ks++) {
            const int rb = 8*(ks & 1);
            unsigned A0, A1, B0, B1;
            if (ks < 2) {
                A0 = cvtpk(s0[rb+0], s0[rb+1]); A1 = cvtpk(s0[rb+2], s0[rb+3]);
                B0 = cvtpk(s0[rb+4], s0[rb+5]); B1 = cvtpk(s0[rb+6], s0[rb+7]);
            } else {
                A0 = cvtpk(s1[rb+0], s1[rb+1]); A1 = cvtpk(s1[rb+2], s1[rb+3]);
                B0 = cvtpk(s1[rb+4], s1[rb+5]); B1 = cvtpk(s1[rb+6], s1[rb+7]);
            }
            asm volatile("v_permlane32_swap_b32 %0, %1" : "+v"(A0), "+v"(B0));
            asm volatile("v_permlane32_swap_b32 %0, %1" : "+v"(A1), "+v"(B1));
            union { s16x8 v; unsigned u[4]; } w;
            w.u[0] = A0; w.u[1] = A1; w.u[2] = B0; w.u[3] = B1;
            pa[ks] = w.v;
        }

        // O^T += V^T * P
        __builtin_amdgcn_s_setprio(1);
        #pragma unroll
        for (int ks = 0; ks < 4; ks++) {
            s16x8 vf0 = *(const s16x8*)(vl + roff[ks]);
            s16x8 vf1 = *(const s16x8*)(vl + roff[4+ks]);
            o0 = MFMA32(vf0, pa[ks], o0);
            o1 = MFMA32(vf1, pa[ks], o1);
        }
        __builtin_amdgcn_s_setprio(0);

        // write next tile into the other buffer, then one barrier
        const int nxt = cur ^ 1;
        *(s16x8*)((char*)Ks[half][nxt] + sd0) = ka;
        *(s16x8*)((char*)Ks[half][nxt] + sd1) = kb2;
        *(s16x8*)((char*)Vs[half][nxt] + sd0) = va;
        *(s16x8*)((char*)Vs[half][nxt] + sd1) = vb2;
        __syncthreads();
        cur = nxt;
    }

    // ---- merge the two K-halves (reuse staging LDS; all loop reads done) ----
    float* OL = (float*)&Ks[0][0][0];               // 32 KB: 4 waves x 64 lanes x 32 f32
    float* ML = (float*)&Vs[0][0][0];               // m at [0..255], l at [256..511]

    if (half == 1) {
        float* ob = OL + ((size_t)(w4*64 + lane))*32;
        #pragma unroll
        for (int i = 0; i < 8; i++) {
            const int slot = (i + (lane & 7)) & 7;  // bank-spread, data idx static
            f32x4 v;
            if (i < 4) { v[0]=o0[4*i]; v[1]=o0[4*i+1]; v[2]=o0[4*i+2]; v[3]=o0[4*i+3]; }
            else { const int j = i-4; v[0]=o1[4*j]; v[1]=o1[4*j+1]; v[2]=o1[4*j+2]; v[3]=o1[4*j+3]; }
            *(f32x4*)(ob + slot*4) = v;
        }
        ML[w4*64 + lane]       = m;
        ML[256 + w4*64 + lane] = l;
    }
    __syncthreads();
    if (half == 0) {
        const float m1 = ML[w4*64 + lane];
        const float l1 = ML[256 + w4*64 + lane];
        const float ms = fmaxf(m, m1);
        const float c0 = exp2f(m - ms), c1 = exp2f(m1 - ms);
        const float inv = 1.0f / (l*c0 + l1*c1);
        const float* ob = OL + ((size_t)(w4*64 + lane))*32;
        const int b = bh >> 4, h = bh & 15;
        float* dst = aout + ((size_t)(b*SEQ + q0 + l31))*DIM + h*HD;
        #pragma unroll
        for (int i = 0; i < 8; i++) {
            const int slot = (i + (lane & 7)) & 7;
            f32x4 p = *(const f32x4*)(ob + slot*4);
            f32x4 w;
            if (i < 4) {
                #pragma unroll
                for (int j = 0; j < 4; j++) w[j] = (o0[4*i+j]*c0 + p[j]*c1) * inv;
                *(f32x4*)(dst + 8*i + 4*hi) = w;
            } else {
                const int t = i - 4;
                #pragma unroll
                for (int j = 0; j < 4; j++) w[j] = (o1[4*t+j]*c0 + p[j]*c1) * inv;
                *(f32x4*)(dst + 32 + 8*t + 4*hi) = w;
            }
        }
    }
}

// ---------------------------------------------------------------------------
extern "C" void kernel_launch(void* const* d_in, const int* in_sizes, int n_in,
                              void* d_out, int out_size, void* d_ws, size_t ws_size,
                              hipStream_t stream)
{
    const float* x     = (const float*)d_in[0];
    const float* Wqkv  = (const float*)d_in[1];
    const float* qg    = (const float*)d_in[2];
    const float* qbeta = (const float*)d_in[3];
    const float* kg    = (const float*)d_in[4];
    const float* kbeta = (const float*)d_in[5];
    const float* Wproj = (const float*)d_in[6];
    const float* bproj = (const float*)d_in[7];
    float* out = (float*)d_out;

    char* ws = (char*)d_ws;
    const size_t qkv_b = (size_t)BATCH*HEADS*SEQ*HD*2;     // 8 MB per tensor
    short* q    = (short*)(ws);
    short* k    = (short*)(ws + qkv_b);
    short* vt   = (short*)(ws + 2*qkv_b);                  // V^T [B,H,D,N]
    short* vrow = (short*)(ws + 3*qkv_b);                  // aliases aout (dead before attn)
    float* aout = (float*)(ws + 3*qkv_b);                  // [ROWS][DIM] fp32

    gemm_kernel<0><<<dim3(3*DIM/BN, ROWS/BM), 256, 0, stream>>>(
        x, Wqkv, nullptr, q, k, vrow, nullptr);

    ln_qk<<<dim3(2*BATCH*HEADS*SEQ/4), 256, 0, stream>>>(q, k, qg, qbeta, kg, kbeta);

    vtrans<<<dim3(BATCH*HEADS, SEQ/64), 256, 0, stream>>>(vrow, vt);

    attn_kernel<<<dim3(BATCH*HEADS, SEQ/128), 512, 0, stream>>>(q, k, vt, aout);

    gemm_kernel<1><<<dim3(DIM/BN, ROWS/BM), 256, 0, stream>>>(
        aout, Wproj, bproj, nullptr, nullptr, nullptr, out);
}

// Round 6
// 146.284 us; speedup vs baseline: 2.1188x; 1.3460x over previous
//
#include <hip/hip_runtime.h>

#define DIM 1024
#define HEADS 16
#define HD 64
#define BATCH 2
#define SEQ 2048
#define ROWS (BATCH*SEQ)          // 4096
#define EPS 1e-6f

typedef float f32x4  __attribute__((ext_vector_type(4)));
typedef float f32x16 __attribute__((ext_vector_type(16)));
typedef short s16x4  __attribute__((ext_vector_type(4)));
typedef short s16x8  __attribute__((ext_vector_type(8)));

static __device__ __forceinline__ short f2bf(float f) {
    union { float f; unsigned u; } x; x.f = f;
    unsigned r = x.u + 0x7FFFu + ((x.u >> 16) & 1u);
    return (short)(r >> 16);
}
static __device__ __forceinline__ s16x8 pack8(float4 lo, float4 hi) {
    s16x8 r;
    r[0]=f2bf(lo.x); r[1]=f2bf(lo.y); r[2]=f2bf(lo.z); r[3]=f2bf(lo.w);
    r[4]=f2bf(hi.x); r[5]=f2bf(hi.y); r[6]=f2bf(hi.z); r[7]=f2bf(hi.w);
    return r;
}
static __device__ __forceinline__ unsigned cvtpk(float a, float b) {
    unsigned r;
    asm("v_cvt_pk_bf16_f32 %0, %1, %2" : "=v"(r) : "v"(a), "v"(b));
    return r;
}
// direct global->LDS DMA, 16B per lane; LDS dest is wave-uniform base + lane*16
static __device__ __forceinline__ void gld16(short* l, const short* g) {
    __builtin_amdgcn_global_load_lds(
        (const __attribute__((address_space(1))) void*)g,
        (__attribute__((address_space(3))) void*)l, 16, 0, 0);
}

#define MFMA32(A,B,C) __builtin_amdgcn_mfma_f32_32x32x16_bf16(A, B, C, 0, 0, 0)
#define MFMA16(A,B,C) __builtin_amdgcn_mfma_f32_16x16x32_bf16(A, B, C, 0, 0, 0)

// ---------------------------------------------------------------------------
// fp32 -> bf16 conversion for x, W_qkv, W_proj (one pass, vectorized)
// ---------------------------------------------------------------------------
__global__ __launch_bounds__(256) void convert3(
    const float* __restrict__ x, const float* __restrict__ wq,
    const float* __restrict__ wp,
    short* __restrict__ xb, short* __restrict__ wqb, short* __restrict__ wpb)
{
    const int idx = blockIdx.x * 256 + threadIdx.x;   // one 8-elem chunk
    const int C1 = 4194304/8, C2 = 3145728/8;
    const float* src; short* dst; int off;
    if (idx < C1)            { src = x;  dst = xb;  off = idx; }
    else if (idx < C1 + C2)  { src = wq; dst = wqb; off = idx - C1; }
    else                     { src = wp; dst = wpb; off = idx - C1 - C2; }
    float4 a = ((const float4*)src)[off*2];
    float4 b = ((const float4*)src)[off*2 + 1];
    ((s16x8*)dst)[off] = pack8(a, b);
}

// ---------------------------------------------------------------------------
// bf16 GEMM, m97 structure: 128x128 tile, BK=64, global_load_lds staging,
// single-buffered LDS, 2 barriers per K-step.
// C[M][N] = A[M][K] * W[N][K]^T.
// MODE 0: fused per-head LayerNorm on q/k, scatter bf16 q/k/v to [B,H,N,D]
// MODE 1: bias add, fp32 out
// ---------------------------------------------------------------------------
#define BKG 64

template<int MODE>
__global__ __launch_bounds__(256) void gemm_bf16(
    const short* __restrict__ A, const short* __restrict__ W,
    const float* __restrict__ bias,
    const float* __restrict__ qg, const float* __restrict__ qbeta,
    const float* __restrict__ kg, const float* __restrict__ kbeta,
    short* __restrict__ qb, short* __restrict__ kb, short* __restrict__ vb,
    float* __restrict__ out)
{
    alignas(16) __shared__ short As[128*BKG];   // [row][64] linear (gld16 dest)
    alignas(16) __shared__ short Bs[128*BKG];
    const int tid  = threadIdx.x;
    const int lane = tid & 63, wave = tid >> 6;
    const int wr = wave >> 1, wc = wave & 1;
    const int c = lane & 15, g = lane >> 4;
    const int brow = blockIdx.y * 128, bcol = blockIdx.x * 128;

    // staging geometry: inst j of wave covers rows (wave*4+j)*8 .. +7
    const int srow = lane >> 3;            // row within 8-row group
    const int scol = (lane & 7) * 8;       // shorts
    const short* ag = A + (size_t)(brow + srow)*DIM + scol;
    const short* wg = W + (size_t)(bcol + srow)*DIM + scol;

    f32x4 acc[4][4] = {};

    for (int k0 = 0; k0 < DIM; k0 += BKG) {
        #pragma unroll
        for (int j = 0; j < 4; j++) {
            const int rg = (wave*4 + j) * 8;           // group base row
            gld16(&As[rg*BKG], ag + (size_t)rg*DIM + k0);
            gld16(&Bs[rg*BKG], wg + (size_t)rg*DIM + k0);
        }
        __syncthreads();

        #pragma unroll
        for (int ks = 0; ks < 2; ks++) {
            s16x8 af[4], bf[4];
            #pragma unroll
            for (int m = 0; m < 4; m++)
                af[m] = *(const s16x8*)&As[(wr*64 + m*16 + c)*BKG + ks*32 + g*8];
            #pragma unroll
            for (int n = 0; n < 4; n++)
                bf[n] = *(const s16x8*)&Bs[(wc*64 + n*16 + c)*BKG + ks*32 + g*8];
            #pragma unroll
            for (int m = 0; m < 4; m++)
                #pragma unroll
                for (int n = 0; n < 4; n++)
                    acc[m][n] = MFMA16(af[m], bf[n], acc[m][n]);
        }
        __syncthreads();
    }

    if (MODE == 0) {
        // wave-column = 64 consecutive cols = exactly one head of one tensor
        const int colbase = bcol + wc*64;
        const int t = colbase >> 10;               // 0:q 1:k 2:v
        const int h = (colbase >> 6) & 15;
        short* dst = (t == 0) ? qb : (t == 1) ? kb : vb;
        float gam[4], bet[4];
        float scale = 1.0f;
        if (t < 2) {
            const float* G  = (t == 0) ? qg : kg;
            const float* Bt = (t == 0) ? qbeta : kbeta;
            #pragma unroll
            for (int n = 0; n < 4; n++) { gam[n] = G[n*16 + c]; bet[n] = Bt[n*16 + c]; }
            if (t == 0) scale = 0.125f * 1.44269504088896340736f;  // D^-0.5 * log2e
        }
        #pragma unroll
        for (int m = 0; m < 4; m++) {
            #pragma unroll
            for (int j = 0; j < 4; j++) {
                const int row = brow + wr*64 + m*16 + g*4 + j;
                const int bi = row >> 11, ni = row & (SEQ-1);
                const size_t rb = ((size_t)(bi*HEADS + h)*SEQ + ni)*HD;
                float v0 = acc[m][0][j], v1 = acc[m][1][j];
                float v2 = acc[m][2][j], v3 = acc[m][3][j];
                if (t < 2) {   // LayerNorm over the 64 head-dims (4 regs x 16 lanes)
                    float s = (v0 + v1) + (v2 + v3);
                    s += __shfl_xor(s, 1); s += __shfl_xor(s, 2);
                    s += __shfl_xor(s, 4); s += __shfl_xor(s, 8);
                    const float mu = s * 0.015625f;
                    v0 -= mu; v1 -= mu; v2 -= mu; v3 -= mu;
                    float vv = (v0*v0 + v1*v1) + (v2*v2 + v3*v3);
                    vv += __shfl_xor(vv, 1); vv += __shfl_xor(vv, 2);
                    vv += __shfl_xor(vv, 4); vv += __shfl_xor(vv, 8);
                    const float rstd = rsqrtf(vv * 0.015625f + EPS);
                    v0 = (v0*rstd*gam[0] + bet[0]) * scale;
                    v1 = (v1*rstd*gam[1] + bet[1]) * scale;
                    v2 = (v2*rstd*gam[2] + bet[2]) * scale;
                    v3 = (v3*rstd*gam[3] + bet[3]) * scale;
                }
                dst[rb + 0*16 + c] = f2bf(v0);
                dst[rb + 1*16 + c] = f2bf(v1);
                dst[rb + 2*16 + c] = f2bf(v2);
                dst[rb + 3*16 + c] = f2bf(v3);
            }
        }
    } else {
        #pragma unroll
        for (int n = 0; n < 4; n++) {
            const int col = bcol + wc*64 + n*16 + c;
            const float bv = bias[col];
            #pragma unroll
            for (int m = 0; m < 4; m++) {
                #pragma unroll
                for (int j = 0; j < 4; j++) {
                    const int row = brow + wr*64 + m*16 + g*4 + j;
                    out[(size_t)row*DIM + col] = acc[m][n][j] + bv;
                }
            }
        }
    }
}

// ---------------------------------------------------------------------------
// V transpose: [B,H,N,D] -> [B,H,D,N] via LDS, coalesced both sides.
// ---------------------------------------------------------------------------
__global__ __launch_bounds__(256) void vtrans(
    const short* __restrict__ vin, short* __restrict__ vt)
{
    constexpr int LT = 72;
    alignas(16) __shared__ short T[64*LT];
    const int bh = blockIdx.x, n0 = blockIdx.y * 64;
    const int t = threadIdx.x;
    const int r = t >> 2, cq = (t & 3) * 16;
    const short* src = vin + ((size_t)bh*SEQ + n0 + r)*HD + cq;
    *(s16x8*)&T[r*LT + cq]     = *(const s16x8*)src;
    *(s16x8*)&T[r*LT + cq + 8] = *(const s16x8*)(src + 8);
    __syncthreads();
    const int d = t >> 2, nq = (t & 3) * 16;
    s16x8 a, b;
    #pragma unroll
    for (int e = 0; e < 8; e++) { a[e] = T[(nq+e)*LT + d]; b[e] = T[(nq+8+e)*LT + d]; }
    short* dst = vt + ((size_t)bh*HD + d)*SEQ + n0 + nq;
    *(s16x8*)dst       = a;
    *(s16x8*)(dst + 8) = b;
}

// ---------------------------------------------------------------------------
// Flash attention, in-block split-K: 8 waves (2 K-halves x 4 q-subtiles).
// Each half: LDS-staged swizzled K/V tiles, double-buffered, 1 barrier/tile.
// Final flash-merge of the two halves through LDS. Writes bf16 aout.
// ---------------------------------------------------------------------------
__global__ __launch_bounds__(512, 4) void attn_kernel(
    const short* __restrict__ qbuf, const short* __restrict__ kbuf,
    const short* __restrict__ vtbuf, short* __restrict__ aout)
{
    alignas(16) __shared__ short Ks[2][2][64*64];   // [half][buf][key][ch]
    alignas(16) __shared__ short Vs[2][2][64*64];   // [half][buf][ch][key]

    const int bh = blockIdx.x;
    const int tid = threadIdx.x;
    const int wave = tid >> 6, lane = tid & 63;
    const int half = wave >> 2, w4 = wave & 3;
    const int l31 = lane & 31, hi = lane >> 5;
    const int q0 = (blockIdx.y * 4 + w4) * 32;
    const size_t base = (size_t)bh * SEQ * HD;
    const short* Q  = qbuf  + base;
    const short* K  = kbuf  + base;
    const short* VT = vtbuf + base;                 // [HD][SEQ]
    const int kt0 = half * (SEQ/2);

    const int t2 = tid & 255;
    const int srow = t2 >> 2;
    const int scol = (t2 & 3) * 16;
    const int sd0 = (srow*128 + scol*2) ^ ((srow & 7) << 4);
    const int sd1 = sd0 ^ 16;

    s16x8 qf[4];
    const short* qrow = Q + (size_t)(q0 + l31)*HD + 8*hi;
    #pragma unroll
    for (int ks = 0; ks < 4; ks++) qf[ks] = *(const s16x8*)(qrow + 16*ks);

    int roff[8];
    #pragma unroll
    for (int ks = 0; ks < 4; ks++) {
        roff[ks]   = (l31*128      + 32*ks + 16*hi) ^ ((l31 & 7) << 4);
        roff[4+ks] = ((32+l31)*128 + 32*ks + 16*hi) ^ ((l31 & 7) << 4);
    }

    f32x16 o0 = {}, o1 = {};
    float m = -1e30f, l = 0.f;

    {
        const short* kg = K  + (size_t)(kt0 + srow)*HD + scol;
        const short* vg = VT + (size_t)srow*SEQ + kt0 + scol;
        s16x8 ka = *(const s16x8*)kg, kb2 = *(const s16x8*)(kg + 8);
        s16x8 va = *(const s16x8*)vg, vb2 = *(const s16x8*)(vg + 8);
        *(s16x8*)((char*)Ks[half][0] + sd0) = ka;
        *(s16x8*)((char*)Ks[half][0] + sd1) = kb2;
        *(s16x8*)((char*)Vs[half][0] + sd0) = va;
        *(s16x8*)((char*)Vs[half][0] + sd1) = vb2;
    }
    __syncthreads();

    int cur = 0;
    for (int i = 0; i < 16; i++) {
        const int ktn = kt0 + ((i + 1) & 15) * 64;
        const short* kg = K  + (size_t)(ktn + srow)*HD + scol;
        const short* vg = VT + (size_t)srow*SEQ + ktn + scol;
        s16x8 ka = *(const s16x8*)kg, kb2 = *(const s16x8*)(kg + 8);
        s16x8 va = *(const s16x8*)vg, vb2 = *(const s16x8*)(vg + 8);

        const char* kl = (const char*)Ks[half][cur];
        const char* vl = (const char*)Vs[half][cur];

        f32x16 s0 = {}, s1 = {};
        __builtin_amdgcn_s_setprio(1);
        #pragma unroll
        for (int ks = 0; ks < 4; ks++) {
            s16x8 kf0 = *(const s16x8*)(kl + roff[ks]);
            s16x8 kf1 = *(const s16x8*)(kl + roff[4+ks]);
            s0 = MFMA32(kf0, qf[ks], s0);
            s1 = MFMA32(kf1, qf[ks], s1);
        }
        __builtin_amdgcn_s_setprio(0);

        float t8[8];
        #pragma unroll
        for (int i2 = 0; i2 < 8; i2++) t8[i2] = fmaxf(fmaxf(s0[i2], s0[i2+8]), fmaxf(s1[i2], s1[i2+8]));
        #pragma unroll
        for (int i2 = 0; i2 < 4; i2++) t8[i2] = fmaxf(t8[i2], t8[i2+4]);
        float pmax = fmaxf(fmaxf(t8[0], t8[2]), fmaxf(t8[1], t8[3]));
        pmax = fmaxf(pmax, __shfl_xor(pmax, 32));

        if (!__all(pmax - m <= 8.0f)) {
            float mn = fmaxf(m, pmax);
            float corr = exp2f(m - mn);
            #pragma unroll
            for (int i2 = 0; i2 < 16; i2++) { o0[i2] *= corr; o1[i2] *= corr; }
            l *= corr;
            m = mn;
        }
        #pragma unroll
        for (int i2 = 0; i2 < 16; i2++) {
            s0[i2] = exp2f(s0[i2] - m);
            s1[i2] = exp2f(s1[i2] - m);
        }
        float a8[8];
        #pragma unroll
        for (int i2 = 0; i2 < 8; i2++) a8[i2] = (s0[i2] + s0[i2+8]) + (s1[i2] + s1[i2+8]);
        #pragma unroll
        for (int i2 = 0; i2 < 4; i2++) a8[i2] += a8[i2+4];
        float rs = (a8[0] + a8[2]) + (a8[1] + a8[3]);
        rs += __shfl_xor(rs, 32);
        l += rs;

        s16x8 pa[4];
        #pragma unroll
        for (int ks = 0; ks < 4; ks++) {
            const int rb = 8*(ks & 1);
            unsigned A0, A1, B0, B1;
            if (ks < 2) {
                A0 = cvtpk(s0[rb+0], s0[rb+1]); A1 = cvtpk(s0[rb+2], s0[rb+3]);
                B0 = cvtpk(s0[rb+4], s0[rb+5]); B1 = cvtpk(s0[rb+6], s0[rb+7]);
            } else {
                A0 = cvtpk(s1[rb+0], s1[rb+1]); A1 = cvtpk(s1[rb+2], s1[rb+3]);
                B0 = cvtpk(s1[rb+4], s1[rb+5]); B1 = cvtpk(s1[rb+6], s1[rb+7]);
            }
            asm volatile("v_permlane32_swap_b32 %0, %1" : "+v"(A0), "+v"(B0));
            asm volatile("v_permlane32_swap_b32 %0, %1" : "+v"(A1), "+v"(B1));
            union { s16x8 v; unsigned u[4]; } w;
            w.u[0] = A0; w.u[1] = A1; w.u[2] = B0; w.u[3] = B1;
            pa[ks] = w.v;
        }

        __builtin_amdgcn_s_setprio(1);
        #pragma unroll
        for (int ks = 0; ks < 4; ks++) {
            s16x8 vf0 = *(const s16x8*)(vl + roff[ks]);
            s16x8 vf1 = *(const s16x8*)(vl + roff[4+ks]);
            o0 = MFMA32(vf0, pa[ks], o0);
            o1 = MFMA32(vf1, pa[ks], o1);
        }
        __builtin_amdgcn_s_setprio(0);

        const int nxt = cur ^ 1;
        *(s16x8*)((char*)Ks[half][nxt] + sd0) = ka;
        *(s16x8*)((char*)Ks[half][nxt] + sd1) = kb2;
        *(s16x8*)((char*)Vs[half][nxt] + sd0) = va;
        *(s16x8*)((char*)Vs[half][nxt] + sd1) = vb2;
        __syncthreads();
        cur = nxt;
    }

    // ---- merge the two K-halves (reuse staging LDS) ----
    float* OL = (float*)&Ks[0][0][0];
    float* ML = (float*)&Vs[0][0][0];

    if (half == 1) {
        float* ob = OL + ((size_t)(w4*64 + lane))*32;
        #pragma unroll
        for (int i = 0; i < 8; i++) {
            const int slot = (i + (lane & 7)) & 7;
            f32x4 v;
            if (i < 4) { v[0]=o0[4*i]; v[1]=o0[4*i+1]; v[2]=o0[4*i+2]; v[3]=o0[4*i+3]; }
            else { const int j = i-4; v[0]=o1[4*j]; v[1]=o1[4*j+1]; v[2]=o1[4*j+2]; v[3]=o1[4*j+3]; }
            *(f32x4*)(ob + slot*4) = v;
        }
        ML[w4*64 + lane]       = m;
        ML[256 + w4*64 + lane] = l;
    }
    __syncthreads();
    if (half == 0) {
        const float m1 = ML[w4*64 + lane];
        const float l1 = ML[256 + w4*64 + lane];
        const float ms = fmaxf(m, m1);
        const float c0 = exp2f(m - ms), c1 = exp2f(m1 - ms);
        const float inv = 1.0f / (l*c0 + l1*c1);
        const float* ob = OL + ((size_t)(w4*64 + lane))*32;
        const int b = bh >> 4, h = bh & 15;
        short* dst = aout + ((size_t)(b*SEQ + q0 + l31))*DIM + h*HD;
        #pragma unroll
        for (int i = 0; i < 8; i++) {
            const int slot = (i + (lane & 7)) & 7;
            f32x4 p = *(const f32x4*)(ob + slot*4);
            s16x4 st;
            if (i < 4) {
                #pragma unroll
                for (int j = 0; j < 4; j++) st[j] = f2bf((o0[4*i+j]*c0 + p[j]*c1) * inv);
                *(s16x4*)(dst + 8*i + 4*hi) = st;
            } else {
                const int t3 = i - 4;
                #pragma unroll
                for (int j = 0; j < 4; j++) st[j] = f2bf((o1[4*t3+j]*c0 + p[j]*c1) * inv);
                *(s16x4*)(dst + 32 + 8*t3 + 4*hi) = st;
            }
        }
    }
}

// ---------------------------------------------------------------------------
extern "C" void kernel_launch(void* const* d_in, const int* in_sizes, int n_in,
                              void* d_out, int out_size, void* d_ws, size_t ws_size,
                              hipStream_t stream)
{
    const float* x     = (const float*)d_in[0];
    const float* Wqkv  = (const float*)d_in[1];
    const float* qg    = (const float*)d_in[2];
    const float* qbeta = (const float*)d_in[3];
    const float* kg    = (const float*)d_in[4];
    const float* kbeta = (const float*)d_in[5];
    const float* Wproj = (const float*)d_in[6];
    const float* bproj = (const float*)d_in[7];
    float* out = (float*)d_out;

    char* ws = (char*)d_ws;
    const size_t MB = 1024*1024;
    short* xb     = (short*)(ws);              // 8 MB  [4096][1024] bf16
    short* aout   = (short*)(ws);              // aliases xb (xb dead before attn)
    short* wqkvb  = (short*)(ws + 8*MB);       // 6 MB  [3072][1024]
    short* wprojb = (short*)(ws + 14*MB);      // 2 MB  [1024][1024]
    short* q      = (short*)(ws + 16*MB);      // 8 MB  [B,H,N,D]
    short* k      = (short*)(ws + 24*MB);      // 8 MB
    short* vrow   = (short*)(ws + 32*MB);      // 8 MB  [B,H,N,D] (dead after vtrans)
    short* vt     = (short*)(ws + 40*MB);      // 8 MB  [B,H,D,N]

    // 1. fp32 -> bf16 conversions
    convert3<<<dim3(4096), 256, 0, stream>>>(x, Wqkv, Wproj, xb, wqkvb, wprojb);

    // 2. QKV GEMM (bf16, global_load_lds) + fused q/k LayerNorm, scatter
    gemm_bf16<0><<<dim3(3*DIM/128, ROWS/128), 256, 0, stream>>>(
        xb, wqkvb, nullptr, qg, qbeta, kg, kbeta, q, k, vrow, nullptr);

    // 3. V transpose
    vtrans<<<dim3(BATCH*HEADS, SEQ/64), 256, 0, stream>>>(vrow, vt);

    // 4. Flash attention (split-K, bf16 out)
    attn_kernel<<<dim3(BATCH*HEADS, SEQ/128), 512, 0, stream>>>(q, k, vt, aout);

    // 5. Projection GEMM + bias -> fp32 d_out
    gemm_bf16<1><<<dim3(DIM/128, ROWS/128), 256, 0, stream>>>(
        aout, wprojb, bproj, nullptr, nullptr, nullptr, nullptr,
        nullptr, nullptr, nullptr, out);
}